// Round 1
// baseline (79.312 us; speedup 1.0000x reference)
//
#include <hip/hip_runtime.h>
#include <math.h>

// Problem constants (from reference setup_inputs): (b,n,h,d) = (4,8192,8,64), fp32.
// Groups: i=0: g=3,r=1,off=0,hmin=0,seg=2048  -> 8192 covered pos/b
//         i=1: g=3,r=2,off=1,hmin=3,seg=4096  -> 4096 covered pos/b (pos%2==1)
//         i=2: g=2,r=4,off=2,hmin=6,seg=8192  -> 2048 covered pos/b (pos%4==2)
#define NB 4
#define NN 8192
#define NH 8
#define ND 64
#define NPART_STRIDE 192       // per-block partial: g*64 floats (max g=3)
#define N_BLOCKS_P1 896        // 4*(128+64+32)

template<int G>
__device__ __forceinline__ void pass1_work(
    const float* __restrict__ Q, const float* __restrict__ K,
    const float* __restrict__ V, float* __restrict__ out,
    float* __restrict__ partials,
    int b, int chunk, int r, int off, int hmin, int seglen)
{
    const int tid  = threadIdx.x;   // 256 threads = 4 waves
    const int w    = tid >> 6;
    const int lane = tid & 63;
    const int sg   = lane >> 4;     // 4 sub-groups of 16 lanes; sub-group = one position
    const int l    = lane & 15;     // lane owns d in [4l, 4l+4)

    float xs[G][4];
    #pragma unroll
    for (int q = 0; q < G; ++q)
        #pragma unroll
        for (int e = 0; e < 4; ++e) xs[q][e] = 0.f;

    const int jwave = chunk * 64 + w * 16;   // this wave's 16 dilated-index slots

    #pragma unroll
    for (int it = 0; it < 4; ++it) {
        const int j   = jwave + it * 4 + sg;       // dilated index within (b,group)
        const int seg = j >> 11;                   // sd == 2048 for all groups
        const int td  = j & 2047;
        const int pos = seg * seglen + off + td * r;
        const size_t rowbase = (((size_t)b * NN + pos) * NH + hmin) * ND;

        float4 qv[G], kv[G], vv[G];
        #pragma unroll
        for (int q = 0; q < G; ++q) {
            qv[q] = *(const float4*)(Q + rowbase + q * ND + 4 * l);
            kv[q] = *(const float4*)(K + rowbase + q * ND + 4 * l);
            vv[q] = *(const float4*)(V + rowbase + q * ND + 4 * l);
        }

        // scores over head axis: sc[q][k] = dot_d(Q[q], K[k]); partial dot per lane
        float sc[G][G];
        #pragma unroll
        for (int q = 0; q < G; ++q)
            #pragma unroll
            for (int k = 0; k < G; ++k)
                sc[q][k] = qv[q].x * kv[k].x + qv[q].y * kv[k].y
                         + qv[q].z * kv[k].z + qv[q].w * kv[k].w;

        // butterfly reduce across the 16 lanes of this sub-group
        #pragma unroll
        for (int o = 8; o >= 1; o >>= 1)
            #pragma unroll
            for (int q = 0; q < G; ++q)
                #pragma unroll
                for (int k = 0; k < G; ++k)
                    sc[q][k] += __shfl_xor(sc[q][k], o);

        // per-lane (redundant) softmax over k, then PV for this lane's d-slice
        #pragma unroll
        for (int q = 0; q < G; ++q) {
            float m = -INFINITY;
            #pragma unroll
            for (int k = 0; k < G; ++k) { sc[q][k] *= 0.125f; m = fmaxf(m, sc[q][k]); }
            float a[G]; float ssum = 0.f;
            #pragma unroll
            for (int k = 0; k < G; ++k) { a[k] = expf(sc[q][k] - m); ssum += a[k]; }
            const float rs = 1.f / ssum;
            float xe0 = 0.f, xe1 = 0.f, xe2 = 0.f, xe3 = 0.f;
            #pragma unroll
            for (int k = 0; k < G; ++k) {
                const float aw = a[k] * rs;
                xe0 += aw * vv[k].x; xe1 += aw * vv[k].y;
                xe2 += aw * vv[k].z; xe3 += aw * vv[k].w;
            }
            // write UNNORMALIZED x to its final (disjoint) output slot
            *(float4*)(out + rowbase + (size_t)q * ND + 4 * l) =
                make_float4(xe0, xe1, xe2, xe3);
            xs[q][0] += xe0; xs[q][1] += xe1; xs[q][2] += xe2; xs[q][3] += xe3;
        }
    }

    // deterministic block reduction of the per-lane partial sums
    __shared__ float red[3][4][4][16][4];   // [q][wave][sg][l][e] = 12 KB
    #pragma unroll
    for (int q = 0; q < G; ++q)
        *(float4*)&red[q][w][sg][l][0] = make_float4(xs[q][0], xs[q][1], xs[q][2], xs[q][3]);
    __syncthreads();

    if (tid < G * 64) {
        const int q  = tid >> 6;
        const int d  = tid & 63;
        const int ll = d >> 2, e = d & 3;
        float s = 0.f;
        #pragma unroll
        for (int ww = 0; ww < 4; ++ww)
            #pragma unroll
            for (int ss = 0; ss < 4; ++ss)
                s += red[q][ww][ss][ll][e];
        partials[(size_t)blockIdx.x * NPART_STRIDE + q * 64 + d] = s;
    }
}

__global__ __launch_bounds__(256)
void sda_pass1(const float* __restrict__ Q, const float* __restrict__ K,
               const float* __restrict__ V, float* __restrict__ out,
               float* __restrict__ partials)
{
    const int bid = blockIdx.x;
    if (bid < 512) {                       // group 0: 4 b * 128 chunks
        const int b = bid >> 7, chunk = bid & 127;
        pass1_work<3>(Q, K, V, out, partials, b, chunk, 1, 0, 0, 2048);
    } else if (bid < 768) {                // group 1: 4 b * 64 chunks
        const int loc = bid - 512;
        const int b = loc >> 6, chunk = loc & 63;
        pass1_work<3>(Q, K, V, out, partials, b, chunk, 2, 1, 3, 4096);
    } else {                               // group 2: 4 b * 32 chunks
        const int loc = bid - 768;
        const int b = loc >> 5, chunk = loc & 31;
        pass1_work<2>(Q, K, V, out, partials, b, chunk, 4, 2, 6, 8192);
    }
}

__global__ __launch_bounds__(256)
void sda_pass2(const float* __restrict__ partials, float* __restrict__ inv)
{
    const int t = blockIdx.x * 256 + threadIdx.x;   // 2048 = b*h*d
    if (t >= NB * NH * ND) return;
    const int b   = t >> 9;
    const int rem = t & 511;
    const int h   = rem >> 6;
    const int d   = rem & 63;
    int qi, start, cnt;
    if (h < 3)      { qi = h;     start = b * 128;       cnt = 128; }
    else if (h < 6) { qi = h - 3; start = 512 + b * 64;  cnt = 64;  }
    else            { qi = h - 6; start = 768 + b * 32;  cnt = 32;  }
    float s = 0.f;
    for (int c = 0; c < cnt; ++c)
        s += partials[(size_t)(start + c) * NPART_STRIDE + qi * 64 + d];
    inv[t] = 1.f / (3.f * (s + 1e-8f));
}

__global__ __launch_bounds__(256)
void sda_pass3(float* __restrict__ out, const float* __restrict__ inv)
{
    const int total4 = NB * NN * NH * ND / 4;   // 4,194,304 float4s
    for (int idx = blockIdx.x * 256 + threadIdx.x; idx < total4;
         idx += gridDim.x * 256) {
        const int d4  = idx & 15;
        const int rem = idx >> 4;
        const int h   = rem & 7;
        const int pos = (rem >> 3) & 8191;
        const int b   = rem >> 16;
        const bool cov = (h < 3) || ((h < 6) ? ((pos & 1) == 1) : ((pos & 3) == 2));
        float4 o;
        if (cov) {
            const float4 v = ((const float4*)out)[idx];
            const float4 f = ((const float4*)inv)[b * 128 + h * 16 + d4];
            o = make_float4(v.x * f.x, v.y * f.y, v.z * f.z, v.w * f.w);
        } else {
            o = make_float4(0.f, 0.f, 0.f, 0.f);
        }
        ((float4*)out)[idx] = o;
    }
}

extern "C" void kernel_launch(void* const* d_in, const int* in_sizes, int n_in,
                              void* d_out, int out_size, void* d_ws, size_t ws_size,
                              hipStream_t stream)
{
    const float* Q = (const float*)d_in[0];
    const float* K = (const float*)d_in[1];
    const float* V = (const float*)d_in[2];
    float* out      = (float*)d_out;
    float* partials = (float*)d_ws;                       // 896*192 floats = 688 KB
    float* inv      = partials + N_BLOCKS_P1 * NPART_STRIDE; // +2048 floats

    hipLaunchKernelGGL(sda_pass1, dim3(N_BLOCKS_P1), dim3(256), 0, stream,
                       Q, K, V, out, partials);
    hipLaunchKernelGGL(sda_pass2, dim3(8), dim3(256), 0, stream, partials, inv);
    hipLaunchKernelGGL(sda_pass3, dim3(2048), dim3(256), 0, stream, out, inv);
}

// Round 2
// 65.080 us; speedup vs baseline: 1.2187x; 1.2187x over previous
//
#include <hip/hip_runtime.h>
#include <math.h>

// (b,n,h,d) = (4,8192,8,64), fp32.
// Groups: i=0: g=3,r=1,off=0,hmin=0,seg=2048  -> 8192 covered pos/b
//         i=1: g=3,r=2,off=1,hmin=3,seg=4096  -> 4096 covered pos/b (pos%2==1)
//         i=2: g=2,r=4,off=2,hmin=6,seg=8192  -> 2048 covered pos/b (pos%4==2)
#define NB 4
#define NN 8192
#define NH 8
#define ND 64
#define NPART_STRIDE 192       // per-block partial: g*64 floats (max g=3)
#define N_BLOCKS_P1 1792       // 4b*(256+128+64) chunks of 32 positions

typedef float Red_t[4][4][16][4];   // [wave][sg][l][e]

template<int G, int IT>
__device__ __forceinline__ void pass1_work(
    const float* __restrict__ Q, const float* __restrict__ K,
    const float* __restrict__ V, float* __restrict__ out,
    float* __restrict__ partials, Red_t* red,
    int b, int chunk, int r, int off, int hmin, int seglen)
{
    const int tid  = threadIdx.x;   // 256 threads = 4 waves
    const int w    = tid >> 6;
    const int lane = tid & 63;
    const int sg   = lane >> 4;     // 16-lane sub-group = one position
    const int l    = lane & 15;     // lane owns d in [4l, 4l+4)

    // ---- address calc for all IT positions, then hoist ALL loads (MLP) ----
    size_t rowbase[IT];
    #pragma unroll
    for (int it = 0; it < IT; ++it) {
        const int j   = chunk * (16 * IT) + w * (4 * IT) + it * 4 + sg;
        const int seg = j >> 11;                 // 2048 dilated pos per segment
        const int td  = j & 2047;
        const int pos = seg * seglen + off + td * r;
        rowbase[it] = (((size_t)b * NN + pos) * NH + hmin) * ND + 4 * l;
    }

    float4 qv[IT][G], kv[IT][G], vv[IT][G];
    #pragma unroll
    for (int it = 0; it < IT; ++it)
        #pragma unroll
        for (int q = 0; q < G; ++q) {
            qv[it][q] = *(const float4*)(Q + rowbase[it] + q * ND);
            kv[it][q] = *(const float4*)(K + rowbase[it] + q * ND);
            vv[it][q] = *(const float4*)(V + rowbase[it] + q * ND);
        }

    float xs[G][4];
    #pragma unroll
    for (int q = 0; q < G; ++q)
        #pragma unroll
        for (int e = 0; e < 4; ++e) xs[q][e] = 0.f;

    #pragma unroll
    for (int it = 0; it < IT; ++it) {
        // scores over head axis: sc[q][k] = dot_d(Q[q], K[k])
        float sc[G][G];
        #pragma unroll
        for (int q = 0; q < G; ++q)
            #pragma unroll
            for (int k = 0; k < G; ++k)
                sc[q][k] = qv[it][q].x * kv[it][k].x + qv[it][q].y * kv[it][k].y
                         + qv[it][q].z * kv[it][k].z + qv[it][q].w * kv[it][k].w;

        // butterfly reduce across the 16 lanes of this sub-group
        #pragma unroll
        for (int o = 8; o >= 1; o >>= 1)
            #pragma unroll
            for (int q = 0; q < G; ++q)
                #pragma unroll
                for (int k = 0; k < G; ++k)
                    sc[q][k] += __shfl_xor(sc[q][k], o);

        // per-lane (redundant) softmax over k, then PV for this lane's d-slice
        #pragma unroll
        for (int q = 0; q < G; ++q) {
            float m = -INFINITY;
            #pragma unroll
            for (int k = 0; k < G; ++k) { sc[q][k] *= 0.125f; m = fmaxf(m, sc[q][k]); }
            float a[G]; float ssum = 0.f;
            #pragma unroll
            for (int k = 0; k < G; ++k) { a[k] = expf(sc[q][k] - m); ssum += a[k]; }
            const float rs = 1.f / ssum;
            float xe0 = 0.f, xe1 = 0.f, xe2 = 0.f, xe3 = 0.f;
            #pragma unroll
            for (int k = 0; k < G; ++k) {
                const float aw = a[k] * rs;
                xe0 += aw * vv[it][k].x; xe1 += aw * vv[it][k].y;
                xe2 += aw * vv[it][k].z; xe3 += aw * vv[it][k].w;
            }
            // write UNNORMALIZED x to its final (disjoint) output slot
            *(float4*)(out + rowbase[it] + (size_t)q * ND) =
                make_float4(xe0, xe1, xe2, xe3);
            xs[q][0] += xe0; xs[q][1] += xe1; xs[q][2] += xe2; xs[q][3] += xe3;
        }
    }

    // deterministic block reduction of the per-lane partial sums
    #pragma unroll
    for (int q = 0; q < G; ++q)
        *(float4*)&red[q][w][sg][l][0] = make_float4(xs[q][0], xs[q][1], xs[q][2], xs[q][3]);
    __syncthreads();

    if (tid < G * 64) {
        const int q  = tid >> 6;
        const int d  = tid & 63;
        const int ll = d >> 2, e = d & 3;
        float s = 0.f;
        #pragma unroll
        for (int ww = 0; ww < 4; ++ww)
            #pragma unroll
            for (int ss = 0; ss < 4; ++ss)
                s += red[q][ww][ss][ll][e];
        partials[(size_t)blockIdx.x * NPART_STRIDE + q * 64 + d] = s;
    }
}

__global__ __launch_bounds__(256)
void sda_pass1(const float* __restrict__ Q, const float* __restrict__ K,
               const float* __restrict__ V, float* __restrict__ out,
               float* __restrict__ partials)
{
    __shared__ Red_t red[3];          // 12 KB, shared by both instantiations
    const int bid = blockIdx.x;
    if (bid < 1024) {                      // group 0: 4 b * 256 chunks
        const int b = bid >> 8, chunk = bid & 255;
        pass1_work<3, 2>(Q, K, V, out, partials, red, b, chunk, 1, 0, 0, 2048);
    } else if (bid < 1536) {               // group 1: 4 b * 128 chunks
        const int loc = bid - 1024;
        const int b = loc >> 7, chunk = loc & 127;
        pass1_work<3, 2>(Q, K, V, out, partials, red, b, chunk, 2, 1, 3, 4096);
    } else {                               // group 2: 4 b * 64 chunks
        const int loc = bid - 1536;
        const int b = loc >> 6, chunk = loc & 63;
        pass1_work<2, 2>(Q, K, V, out, partials, red, b, chunk, 4, 2, 6, 8192);
    }
}

__global__ __launch_bounds__(256)
void sda_pass2(const float* __restrict__ partials, float* __restrict__ inv)
{
    const int bh = blockIdx.x;            // 32 blocks = b*8+h
    const int b  = bh >> 3;
    const int h  = bh & 7;
    const int d    = threadIdx.x & 63;
    const int part = threadIdx.x >> 6;    // 4-way split of the chunk list
    int qi, start, cnt;
    if (h < 3)      { qi = h;     start = b * 256;        cnt = 256; }
    else if (h < 6) { qi = h - 3; start = 1024 + b * 128; cnt = 128; }
    else            { qi = h - 6; start = 1536 + b * 64;  cnt = 64;  }
    float s = 0.f;
    for (int c = part; c < cnt; c += 4)
        s += partials[(size_t)(start + c) * NPART_STRIDE + qi * 64 + d];
    __shared__ float sred[4][64];
    sred[part][d] = s;
    __syncthreads();
    if (part == 0) {
        const float tot = sred[0][d] + sred[1][d] + sred[2][d] + sred[3][d];
        inv[bh * 64 + d] = 1.f / (3.f * (tot + 1e-8f));
    }
}

__global__ __launch_bounds__(256)
void sda_pass3(float* __restrict__ out, const float* __restrict__ inv)
{
    const int total4 = NB * NN * NH * ND / 4;   // 4,194,304 float4s
    for (int idx = blockIdx.x * 256 + threadIdx.x; idx < total4;
         idx += gridDim.x * 256) {
        const int d4  = idx & 15;
        const int rem = idx >> 4;
        const int h   = rem & 7;
        const int pos = (rem >> 3) & 8191;
        const int b   = rem >> 16;
        const bool cov = (h < 3) || ((h < 6) ? ((pos & 1) == 1) : ((pos & 3) == 2));
        float4 o;
        if (cov) {
            const float4 v = ((const float4*)out)[idx];
            const float4 f = ((const float4*)inv)[b * 128 + h * 16 + d4];
            o = make_float4(v.x * f.x, v.y * f.y, v.z * f.z, v.w * f.w);
        } else {
            o = make_float4(0.f, 0.f, 0.f, 0.f);
        }
        ((float4*)out)[idx] = o;
    }
}

extern "C" void kernel_launch(void* const* d_in, const int* in_sizes, int n_in,
                              void* d_out, int out_size, void* d_ws, size_t ws_size,
                              hipStream_t stream)
{
    const float* Q = (const float*)d_in[0];
    const float* K = (const float*)d_in[1];
    const float* V = (const float*)d_in[2];
    float* out      = (float*)d_out;
    float* partials = (float*)d_ws;                          // 1792*192*4 B ≈ 1.38 MB
    float* inv      = partials + N_BLOCKS_P1 * NPART_STRIDE; // +2048 floats

    hipLaunchKernelGGL(sda_pass1, dim3(N_BLOCKS_P1), dim3(256), 0, stream,
                       Q, K, V, out, partials);
    hipLaunchKernelGGL(sda_pass2, dim3(32), dim3(256), 0, stream, partials, inv);
    hipLaunchKernelGGL(sda_pass3, dim3(2048), dim3(256), 0, stream, out, inv);
}

// Round 3
// 65.079 us; speedup vs baseline: 1.2187x; 1.0000x over previous
//
#include <hip/hip_runtime.h>
#include <math.h>

// (b,n,h,d) = (4,8192,8,64), fp32.
// Groups: i=0: g=3,r=1,off=0,hmin=0,seg=2048  -> 8192 covered pos/b
//         i=1: g=3,r=2,off=1,hmin=3,seg=4096  -> 4096 covered pos/b (pos%2==1)
//         i=2: g=2,r=4,off=2,hmin=6,seg=8192  -> 2048 covered pos/b (pos%4==2)
#define NB 4
#define NN 8192
#define NH 8
#define ND 64
#define NPART_STRIDE 192       // per-block partial: g*64 floats (max g=3)
#define N_BLOCKS_P1 1792       // 4b*(256+128+64) chunks of 32 positions

typedef float Red_t[4][4][16][4];   // [wave][sg][l][e]

#define PIN4(v) "+v"(v.x), "+v"(v.y), "+v"(v.z), "+v"(v.w)

template<int G, int IT>
__device__ __forceinline__ void pass1_work(
    const float* __restrict__ Q, const float* __restrict__ K,
    const float* __restrict__ V, float* __restrict__ out,
    float* __restrict__ partials, Red_t* red,
    int b, int chunk, int r, int off, int hmin, int seglen)
{
    const int tid  = threadIdx.x;   // 256 threads = 4 waves
    const int w    = tid >> 6;
    const int lane = tid & 63;
    const int sg   = lane >> 4;     // 16-lane sub-group = one position
    const int l    = lane & 15;     // lane owns d in [4l, 4l+4)

    size_t rowbase[IT];
    #pragma unroll
    for (int it = 0; it < IT; ++it) {
        const int j   = chunk * (16 * IT) + w * (4 * IT) + it * 4 + sg;
        const int seg = j >> 11;                 // 2048 dilated pos per segment
        const int td  = j & 2047;
        const int pos = seg * seglen + off + td * r;
        rowbase[it] = (((size_t)b * NN + pos) * NH + hmin) * ND + 4 * l;
    }

    // ---- issue ALL loads (Q, then K, then V), then pin them live so the
    // compiler cannot re-sink/serialize them (R2: it allocated 36 VGPRs and
    // serialized -> 1.78 TB/s latency-bound). 18 float4 = 72 VGPRs forced. ----
    float4 qv[IT][G], kv[IT][G], vv[IT][G];
    #pragma unroll
    for (int it = 0; it < IT; ++it)
        #pragma unroll
        for (int q = 0; q < G; ++q)
            qv[it][q] = *(const float4*)(Q + rowbase[it] + q * ND);
    #pragma unroll
    for (int it = 0; it < IT; ++it)
        #pragma unroll
        for (int q = 0; q < G; ++q)
            kv[it][q] = *(const float4*)(K + rowbase[it] + q * ND);
    #pragma unroll
    for (int it = 0; it < IT; ++it)
        #pragma unroll
        for (int q = 0; q < G; ++q)
            vv[it][q] = *(const float4*)(V + rowbase[it] + q * ND);

    if constexpr (G == 3) {
        asm volatile("" : PIN4(qv[0][0]), PIN4(qv[0][1]), PIN4(qv[0][2]),
                          PIN4(qv[1][0]), PIN4(qv[1][1]), PIN4(qv[1][2]));
        asm volatile("" : PIN4(kv[0][0]), PIN4(kv[0][1]), PIN4(kv[0][2]),
                          PIN4(kv[1][0]), PIN4(kv[1][1]), PIN4(kv[1][2]));
        asm volatile("" : PIN4(vv[0][0]), PIN4(vv[0][1]), PIN4(vv[0][2]),
                          PIN4(vv[1][0]), PIN4(vv[1][1]), PIN4(vv[1][2]));
    } else {
        asm volatile("" : PIN4(qv[0][0]), PIN4(qv[0][1]),
                          PIN4(qv[1][0]), PIN4(qv[1][1]));
        asm volatile("" : PIN4(kv[0][0]), PIN4(kv[0][1]),
                          PIN4(kv[1][0]), PIN4(kv[1][1]));
        asm volatile("" : PIN4(vv[0][0]), PIN4(vv[0][1]),
                          PIN4(vv[1][0]), PIN4(vv[1][1]));
    }

    float xs[G][4];
    #pragma unroll
    for (int q = 0; q < G; ++q)
        #pragma unroll
        for (int e = 0; e < 4; ++e) xs[q][e] = 0.f;

    #pragma unroll
    for (int it = 0; it < IT; ++it) {
        // scores over head axis: sc[q][k] = dot_d(Q[q], K[k])
        float sc[G][G];
        #pragma unroll
        for (int q = 0; q < G; ++q)
            #pragma unroll
            for (int k = 0; k < G; ++k)
                sc[q][k] = qv[it][q].x * kv[it][k].x + qv[it][q].y * kv[it][k].y
                         + qv[it][q].z * kv[it][k].z + qv[it][q].w * kv[it][k].w;

        // butterfly reduce across the 16 lanes of this sub-group
        #pragma unroll
        for (int o = 8; o >= 1; o >>= 1)
            #pragma unroll
            for (int q = 0; q < G; ++q)
                #pragma unroll
                for (int k = 0; k < G; ++k)
                    sc[q][k] += __shfl_xor(sc[q][k], o);

        // per-lane (redundant) softmax over k, then PV for this lane's d-slice
        #pragma unroll
        for (int q = 0; q < G; ++q) {
            float m = -INFINITY;
            #pragma unroll
            for (int k = 0; k < G; ++k) { sc[q][k] *= 0.125f; m = fmaxf(m, sc[q][k]); }
            float a[G]; float ssum = 0.f;
            #pragma unroll
            for (int k = 0; k < G; ++k) { a[k] = __expf(sc[q][k] - m); ssum += a[k]; }
            const float rs = 1.f / ssum;
            float xe0 = 0.f, xe1 = 0.f, xe2 = 0.f, xe3 = 0.f;
            #pragma unroll
            for (int k = 0; k < G; ++k) {
                const float aw = a[k] * rs;
                xe0 += aw * vv[it][k].x; xe1 += aw * vv[it][k].y;
                xe2 += aw * vv[it][k].z; xe3 += aw * vv[it][k].w;
            }
            // write UNNORMALIZED x to its final (disjoint) output slot
            *(float4*)(out + rowbase[it] + (size_t)q * ND) =
                make_float4(xe0, xe1, xe2, xe3);
            xs[q][0] += xe0; xs[q][1] += xe1; xs[q][2] += xe2; xs[q][3] += xe3;
        }
    }

    // deterministic block reduction of the per-lane partial sums
    #pragma unroll
    for (int q = 0; q < G; ++q)
        *(float4*)&red[q][w][sg][l][0] = make_float4(xs[q][0], xs[q][1], xs[q][2], xs[q][3]);
    __syncthreads();

    if (tid < G * 64) {
        const int q  = tid >> 6;
        const int d  = tid & 63;
        const int ll = d >> 2, e = d & 3;
        float s = 0.f;
        #pragma unroll
        for (int ww = 0; ww < 4; ++ww)
            #pragma unroll
            for (int ss = 0; ss < 4; ++ss)
                s += red[q][ww][ss][ll][e];
        partials[(size_t)blockIdx.x * NPART_STRIDE + q * 64 + d] = s;
    }
}

__global__ __launch_bounds__(256, 4)
void sda_pass1(const float* __restrict__ Q, const float* __restrict__ K,
               const float* __restrict__ V, float* __restrict__ out,
               float* __restrict__ partials)
{
    __shared__ Red_t red[3];          // 12 KB, shared by both instantiations
    const int bid = blockIdx.x;
    if (bid < 1024) {                      // group 0: 4 b * 256 chunks
        const int b = bid >> 8, chunk = bid & 255;
        pass1_work<3, 2>(Q, K, V, out, partials, red, b, chunk, 1, 0, 0, 2048);
    } else if (bid < 1536) {               // group 1: 4 b * 128 chunks
        const int loc = bid - 1024;
        const int b = loc >> 7, chunk = loc & 127;
        pass1_work<3, 2>(Q, K, V, out, partials, red, b, chunk, 2, 1, 3, 4096);
    } else {                               // group 2: 4 b * 64 chunks
        const int loc = bid - 1536;
        const int b = loc >> 6, chunk = loc & 63;
        pass1_work<2, 2>(Q, K, V, out, partials, red, b, chunk, 4, 2, 6, 8192);
    }
}

__global__ __launch_bounds__(256)
void sda_pass2(const float* __restrict__ partials, float* __restrict__ inv)
{
    const int bh = blockIdx.x;            // 32 blocks = b*8+h
    const int b  = bh >> 3;
    const int h  = bh & 7;
    const int d    = threadIdx.x & 63;
    const int part = threadIdx.x >> 6;    // 4-way split of the chunk list
    int qi, start, cnt;
    if (h < 3)      { qi = h;     start = b * 256;        cnt = 256; }
    else if (h < 6) { qi = h - 3; start = 1024 + b * 128; cnt = 128; }
    else            { qi = h - 6; start = 1536 + b * 64;  cnt = 64;  }
    float s = 0.f;
    for (int c = part; c < cnt; c += 4)
        s += partials[(size_t)(start + c) * NPART_STRIDE + qi * 64 + d];
    __shared__ float sred[4][64];
    sred[part][d] = s;
    __syncthreads();
    if (part == 0) {
        const float tot = sred[0][d] + sred[1][d] + sred[2][d] + sred[3][d];
        inv[bh * 64 + d] = 1.f / (3.f * (tot + 1e-8f));
    }
}

__global__ __launch_bounds__(256)
void sda_pass3(float* __restrict__ out, const float* __restrict__ inv)
{
    const int total4 = NB * NN * NH * ND / 4;   // 4,194,304 float4s
    for (int idx = blockIdx.x * 256 + threadIdx.x; idx < total4;
         idx += gridDim.x * 256) {
        const int d4  = idx & 15;
        const int rem = idx >> 4;
        const int h   = rem & 7;
        const int pos = (rem >> 3) & 8191;
        const int b   = rem >> 16;
        const bool cov = (h < 3) || ((h < 6) ? ((pos & 1) == 1) : ((pos & 3) == 2));
        float4 o;
        if (cov) {
            const float4 v = ((const float4*)out)[idx];
            const float4 f = ((const float4*)inv)[b * 128 + h * 16 + d4];
            o = make_float4(v.x * f.x, v.y * f.y, v.z * f.z, v.w * f.w);
        } else {
            o = make_float4(0.f, 0.f, 0.f, 0.f);
        }
        ((float4*)out)[idx] = o;
    }
}

extern "C" void kernel_launch(void* const* d_in, const int* in_sizes, int n_in,
                              void* d_out, int out_size, void* d_ws, size_t ws_size,
                              hipStream_t stream)
{
    const float* Q = (const float*)d_in[0];
    const float* K = (const float*)d_in[1];
    const float* V = (const float*)d_in[2];
    float* out      = (float*)d_out;
    float* partials = (float*)d_ws;                          // 1792*192*4 B ≈ 1.38 MB
    float* inv      = partials + N_BLOCKS_P1 * NPART_STRIDE; // +2048 floats

    hipLaunchKernelGGL(sda_pass1, dim3(N_BLOCKS_P1), dim3(256), 0, stream,
                       Q, K, V, out, partials);
    hipLaunchKernelGGL(sda_pass2, dim3(32), dim3(256), 0, stream, partials, inv);
    hipLaunchKernelGGL(sda_pass3, dim3(2048), dim3(256), 0, stream, out, inv);
}

// Round 4
// 64.818 us; speedup vs baseline: 1.2236x; 1.0040x over previous
//
#include <hip/hip_runtime.h>
#include <math.h>

// (b,n,h,d) = (4,8192,8,64), fp32.
// Groups: i=0: g=3,r=1,off=0,hmin=0,seg=2048  -> 8192 covered pos/b
//         i=1: g=3,r=2,off=1,hmin=3,seg=4096  -> 4096 covered pos/b (pos%2==1)
//         i=2: g=2,r=4,off=2,hmin=6,seg=8192  -> 2048 covered pos/b (pos%4==2)
#define NB 4
#define NN 8192
#define NH 8
#define ND 64
#define NPART_STRIDE 192       // per-block partial: g*64 floats (max g=3)
#define N_BLOCKS_P1 1792       // 4b*(256+128+64) chunks of 32 positions

typedef float f32x4 __attribute__((ext_vector_type(4)));

typedef float Red_t[4][4][16][4];   // [wave][sg][l][e]

template<int G, int IT>
__device__ __forceinline__ void pass1_work(
    const float* __restrict__ Q, const float* __restrict__ K,
    const float* __restrict__ V, float* __restrict__ out,
    float* __restrict__ partials, Red_t* red,
    int b, int chunk, int r, int off, int hmin, int seglen)
{
    const int tid  = threadIdx.x;   // 256 threads = 4 waves
    const int w    = tid >> 6;
    const int lane = tid & 63;
    const int sg   = lane >> 4;     // 16-lane sub-group = one position
    const int l    = lane & 15;     // lane owns d in [4l, 4l+4)

    size_t rowbase[IT];
    #pragma unroll
    for (int it = 0; it < IT; ++it) {
        const int j   = chunk * (16 * IT) + w * (4 * IT) + it * 4 + sg;
        const int seg = j >> 11;                 // 2048 dilated pos per segment
        const int td  = j & 2047;
        const int pos = seg * seglen + off + td * r;
        rowbase[it] = (((size_t)b * NN + pos) * NH + hmin) * ND + 4 * l;
    }

    // ---- ISA-forced MLP: issue ALL loads back-to-back in one asm block.
    // R2/R3: the allocator (36/52 VGPRs) re-serialized source-level hoists.
    // Here 18 "=&v" quads force 18 outstanding global_load_dwordx4.
    // End with vmcnt(G*IT) so the V loads stay in flight under the
    // dot/butterfly/softmax phase; drain before PV (rule #18 pattern).
    f32x4 qv[IT][G], kv[IT][G], vv[IT][G];
    static_assert(IT == 2, "asm block assumes IT==2");
    if constexpr (G == 3) {
        asm volatile(
            "global_load_dwordx4 %0, %[a0], off\n\t"
            "global_load_dwordx4 %1, %[a0], off offset:256\n\t"
            "global_load_dwordx4 %2, %[a0], off offset:512\n\t"
            "global_load_dwordx4 %3, %[a1], off\n\t"
            "global_load_dwordx4 %4, %[a1], off offset:256\n\t"
            "global_load_dwordx4 %5, %[a1], off offset:512\n\t"
            "global_load_dwordx4 %6, %[a2], off\n\t"
            "global_load_dwordx4 %7, %[a2], off offset:256\n\t"
            "global_load_dwordx4 %8, %[a2], off offset:512\n\t"
            "global_load_dwordx4 %9, %[a3], off\n\t"
            "global_load_dwordx4 %10, %[a3], off offset:256\n\t"
            "global_load_dwordx4 %11, %[a3], off offset:512\n\t"
            "global_load_dwordx4 %12, %[a4], off\n\t"
            "global_load_dwordx4 %13, %[a4], off offset:256\n\t"
            "global_load_dwordx4 %14, %[a4], off offset:512\n\t"
            "global_load_dwordx4 %15, %[a5], off\n\t"
            "global_load_dwordx4 %16, %[a5], off offset:256\n\t"
            "global_load_dwordx4 %17, %[a5], off offset:512\n\t"
            "s_waitcnt vmcnt(6)"
            : "=&v"(qv[0][0]), "=&v"(qv[0][1]), "=&v"(qv[0][2]),
              "=&v"(qv[1][0]), "=&v"(qv[1][1]), "=&v"(qv[1][2]),
              "=&v"(kv[0][0]), "=&v"(kv[0][1]), "=&v"(kv[0][2]),
              "=&v"(kv[1][0]), "=&v"(kv[1][1]), "=&v"(kv[1][2]),
              "=&v"(vv[0][0]), "=&v"(vv[0][1]), "=&v"(vv[0][2]),
              "=&v"(vv[1][0]), "=&v"(vv[1][1]), "=&v"(vv[1][2])
            : [a0]"v"(Q + rowbase[0]), [a1]"v"(Q + rowbase[1]),
              [a2]"v"(K + rowbase[0]), [a3]"v"(K + rowbase[1]),
              [a4]"v"(V + rowbase[0]), [a5]"v"(V + rowbase[1]));
    } else {
        asm volatile(
            "global_load_dwordx4 %0, %[a0], off\n\t"
            "global_load_dwordx4 %1, %[a0], off offset:256\n\t"
            "global_load_dwordx4 %2, %[a1], off\n\t"
            "global_load_dwordx4 %3, %[a1], off offset:256\n\t"
            "global_load_dwordx4 %4, %[a2], off\n\t"
            "global_load_dwordx4 %5, %[a2], off offset:256\n\t"
            "global_load_dwordx4 %6, %[a3], off\n\t"
            "global_load_dwordx4 %7, %[a3], off offset:256\n\t"
            "global_load_dwordx4 %8, %[a4], off\n\t"
            "global_load_dwordx4 %9, %[a4], off offset:256\n\t"
            "global_load_dwordx4 %10, %[a5], off\n\t"
            "global_load_dwordx4 %11, %[a5], off offset:256\n\t"
            "s_waitcnt vmcnt(4)"
            : "=&v"(qv[0][0]), "=&v"(qv[0][1]),
              "=&v"(qv[1][0]), "=&v"(qv[1][1]),
              "=&v"(kv[0][0]), "=&v"(kv[0][1]),
              "=&v"(kv[1][0]), "=&v"(kv[1][1]),
              "=&v"(vv[0][0]), "=&v"(vv[0][1]),
              "=&v"(vv[1][0]), "=&v"(vv[1][1])
            : [a0]"v"(Q + rowbase[0]), [a1]"v"(Q + rowbase[1]),
              [a2]"v"(K + rowbase[0]), [a3]"v"(K + rowbase[1]),
              [a4]"v"(V + rowbase[0]), [a5]"v"(V + rowbase[1]));
    }

    // ---- phase 1: dots + butterfly + softmax weights (Q,K only) ----
    float sc[IT][G][G];
    #pragma unroll
    for (int it = 0; it < IT; ++it) {
        #pragma unroll
        for (int q = 0; q < G; ++q)
            #pragma unroll
            for (int k = 0; k < G; ++k)
                sc[it][q][k] = qv[it][q][0] * kv[it][k][0] + qv[it][q][1] * kv[it][k][1]
                             + qv[it][q][2] * kv[it][k][2] + qv[it][q][3] * kv[it][k][3];

        #pragma unroll
        for (int o = 8; o >= 1; o >>= 1)
            #pragma unroll
            for (int q = 0; q < G; ++q)
                #pragma unroll
                for (int k = 0; k < G; ++k)
                    sc[it][q][k] += __shfl_xor(sc[it][q][k], o);

        #pragma unroll
        for (int q = 0; q < G; ++q) {
            float m = -INFINITY;
            #pragma unroll
            for (int k = 0; k < G; ++k) { sc[it][q][k] *= 0.125f; m = fmaxf(m, sc[it][q][k]); }
            float ssum = 0.f;
            #pragma unroll
            for (int k = 0; k < G; ++k) { sc[it][q][k] = __expf(sc[it][q][k] - m); ssum += sc[it][q][k]; }
            const float rs = 1.f / ssum;
            #pragma unroll
            for (int k = 0; k < G; ++k) sc[it][q][k] *= rs;   // normalized weight
        }
    }

    // ---- drain V loads; fence so PV's register reads can't hoist above ----
    asm volatile("s_waitcnt vmcnt(0)" ::: "memory");
    __builtin_amdgcn_sched_barrier(0);

    // ---- phase 2: PV + store + partial-sum accumulate ----
    float xs[G][4];
    #pragma unroll
    for (int q = 0; q < G; ++q)
        #pragma unroll
        for (int e = 0; e < 4; ++e) xs[q][e] = 0.f;

    #pragma unroll
    for (int it = 0; it < IT; ++it) {
        #pragma unroll
        for (int q = 0; q < G; ++q) {
            float xe0 = 0.f, xe1 = 0.f, xe2 = 0.f, xe3 = 0.f;
            #pragma unroll
            for (int k = 0; k < G; ++k) {
                const float aw = sc[it][q][k];
                xe0 += aw * vv[it][k][0]; xe1 += aw * vv[it][k][1];
                xe2 += aw * vv[it][k][2]; xe3 += aw * vv[it][k][3];
            }
            *(float4*)(out + rowbase[it] + (size_t)q * ND) =
                make_float4(xe0, xe1, xe2, xe3);
            xs[q][0] += xe0; xs[q][1] += xe1; xs[q][2] += xe2; xs[q][3] += xe3;
        }
    }

    // deterministic block reduction of the per-lane partial sums
    #pragma unroll
    for (int q = 0; q < G; ++q)
        *(float4*)&red[q][w][sg][l][0] = make_float4(xs[q][0], xs[q][1], xs[q][2], xs[q][3]);
    __syncthreads();

    if (tid < G * 64) {
        const int q  = tid >> 6;
        const int d  = tid & 63;
        const int ll = d >> 2, e = d & 3;
        float s = 0.f;
        #pragma unroll
        for (int ww = 0; ww < 4; ++ww)
            #pragma unroll
            for (int ss = 0; ss < 4; ++ss)
                s += red[q][ww][ss][ll][e];
        partials[(size_t)blockIdx.x * NPART_STRIDE + q * 64 + d] = s;
    }
}

__global__ __launch_bounds__(256)
void sda_pass1(const float* __restrict__ Q, const float* __restrict__ K,
               const float* __restrict__ V, float* __restrict__ out,
               float* __restrict__ partials)
{
    __shared__ Red_t red[3];          // 12 KB, shared by both instantiations
    const int bid = blockIdx.x;
    if (bid < 1024) {                      // group 0: 4 b * 256 chunks
        const int b = bid >> 8, chunk = bid & 255;
        pass1_work<3, 2>(Q, K, V, out, partials, red, b, chunk, 1, 0, 0, 2048);
    } else if (bid < 1536) {               // group 1: 4 b * 128 chunks
        const int loc = bid - 1024;
        const int b = loc >> 7, chunk = loc & 127;
        pass1_work<3, 2>(Q, K, V, out, partials, red, b, chunk, 2, 1, 3, 4096);
    } else {                               // group 2: 4 b * 64 chunks
        const int loc = bid - 1536;
        const int b = loc >> 6, chunk = loc & 63;
        pass1_work<2, 2>(Q, K, V, out, partials, red, b, chunk, 4, 2, 6, 8192);
    }
}

__global__ __launch_bounds__(256)
void sda_pass2(const float* __restrict__ partials, float* __restrict__ inv)
{
    const int bh = blockIdx.x;            // 32 blocks = b*8+h
    const int b  = bh >> 3;
    const int h  = bh & 7;
    const int d    = threadIdx.x & 63;
    const int part = threadIdx.x >> 6;    // 4-way split of the chunk list
    int qi, start, cnt;
    if (h < 3)      { qi = h;     start = b * 256;        cnt = 256; }
    else if (h < 6) { qi = h - 3; start = 1024 + b * 128; cnt = 128; }
    else            { qi = h - 6; start = 1536 + b * 64;  cnt = 64;  }
    float s = 0.f;
    for (int c = part; c < cnt; c += 4)
        s += partials[(size_t)(start + c) * NPART_STRIDE + qi * 64 + d];
    __shared__ float sred[4][64];
    sred[part][d] = s;
    __syncthreads();
    if (part == 0) {
        const float tot = sred[0][d] + sred[1][d] + sred[2][d] + sred[3][d];
        inv[bh * 64 + d] = 1.f / (3.f * (tot + 1e-8f));
    }
}

__global__ __launch_bounds__(256)
void sda_pass3(float* __restrict__ out, const float* __restrict__ inv)
{
    const int total4 = NB * NN * NH * ND / 4;   // 4,194,304 float4s
    for (int idx = blockIdx.x * 256 + threadIdx.x; idx < total4;
         idx += gridDim.x * 256) {
        const int d4  = idx & 15;
        const int rem = idx >> 4;
        const int h   = rem & 7;
        const int pos = (rem >> 3) & 8191;
        const int b   = rem >> 16;
        const bool cov = (h < 3) || ((h < 6) ? ((pos & 1) == 1) : ((pos & 3) == 2));
        float4 o;
        if (cov) {
            const float4 v = ((const float4*)out)[idx];
            const float4 f = ((const float4*)inv)[b * 128 + h * 16 + d4];
            o = make_float4(v.x * f.x, v.y * f.y, v.z * f.z, v.w * f.w);
        } else {
            o = make_float4(0.f, 0.f, 0.f, 0.f);
        }
        ((float4*)out)[idx] = o;
    }
}

extern "C" void kernel_launch(void* const* d_in, const int* in_sizes, int n_in,
                              void* d_out, int out_size, void* d_ws, size_t ws_size,
                              hipStream_t stream)
{
    const float* Q = (const float*)d_in[0];
    const float* K = (const float*)d_in[1];
    const float* V = (const float*)d_in[2];
    float* out      = (float*)d_out;
    float* partials = (float*)d_ws;                          // 1792*192*4 B ≈ 1.38 MB
    float* inv      = partials + N_BLOCKS_P1 * NPART_STRIDE; // +2048 floats

    hipLaunchKernelGGL(sda_pass1, dim3(N_BLOCKS_P1), dim3(256), 0, stream,
                       Q, K, V, out, partials);
    hipLaunchKernelGGL(sda_pass2, dim3(32), dim3(256), 0, stream, partials, inv);
    hipLaunchKernelGGL(sda_pass3, dim3(2048), dim3(256), 0, stream, out, inv);
}